// Round 21
// baseline (218.889 us; speedup 1.0000x reference)
//
#include <hip/hip_runtime.h>
#include <cstdint>

#define DEV static __device__ __forceinline__

typedef unsigned short u16;
typedef unsigned int u32;
typedef __attribute__((ext_vector_type(8))) _Float16 half8;
typedef __attribute__((ext_vector_type(4))) float f32x4;
typedef __attribute__((ext_vector_type(4))) unsigned short u16x4;

DEV u16 f2h_bits(float f) {
  _Float16 h = (_Float16)f;
  union { _Float16 h; u16 u; } cv; cv.h = h; return cv.u;
}

DEV u32 pack2h(float a, float b) {
  union { __fp16 __attribute__((ext_vector_type(2))) h; u32 u; } cv;
  cv.h = __builtin_amdgcn_cvt_pkrtz(a, b);
  return cv.u;
}

#define EXP2 __builtin_amdgcn_exp2f   // raw v_exp_f32 (exp2f = ~10 instr via OCML)

DEV void async_cp16(const void* g, void* l) {
  __builtin_amdgcn_global_load_lds(
      (const __attribute__((address_space(1))) void*)g,
      (__attribute__((address_space(3))) void*)l, 16, 0, 0);
}

// ---------------- 3x fused fp32 -> fp16 convert (one streaming launch) ----------------
struct CParams { const float4* in[3]; u16* out[3]; };

__global__ void cvt3(CParams p) {
  const int w = blockIdx.x >> 13;                  // 8192 blocks per tensor
  const int i = (blockIdx.x & 8191) * 256 + threadIdx.x;
  float4 f = p.in[w][i];
  u16x4 u;
  u.x = f2h_bits(f.x); u.y = f2h_bits(f.y); u.z = f2h_bits(f.z); u.w = f2h_bits(f.w);
  *(u16x4*)(p.out[w] + i * 4) = u;
}

// ---------------- 4x fused W [K][N] fp32 -> Wt [N][K] fp16 ----------------
struct TParams { const float* W[4]; u16* out[4]; };

__global__ void tcvt4(TParams p) {
  __shared__ float tile[32][33];
  const int w = blockIdx.x >> 10;
  const int bidx = blockIdx.x & 1023;
  const float* __restrict__ Wf = p.W[w];
  u16* __restrict__ Wt = p.out[w];
  const int bx = bidx & 31, by = bidx >> 5;
  const int tx = threadIdx.x & 31, ty = threadIdx.x >> 5;
#pragma unroll
  for (int r = 0; r < 32; r += 8)
    tile[ty + r][tx] = Wf[(by * 32 + ty + r) * 1024 + bx * 32 + tx];
  __syncthreads();
#pragma unroll
  for (int r = 0; r < 32; r += 8)
    Wt[(bx * 32 + ty + r) * 1024 + by * 32 + tx] = f2h_bits(tile[tx][ty + r]);
}

// ======== GEMM v3: 256x128 tile, 8 waves, BK=64, 3-buffer counted vmcnt(6) ========
// C[8192,1024] = A_f16 * Bt_f16^T (+bias); runtime epi:
// 0: qh fp16 *0.125*log2e  1: kh fp16  2: vt fp16 transposed  3: f32 row-major
DEV void gemm_body(const u16* __restrict__ A, const u16* __restrict__ Bt,
                   const float* __restrict__ bias, const int epi, void* __restrict__ outv,
                   u16 (*As)[16384], u16 (*Bs)[8192])
{
  const int tid = threadIdx.x;
  const int wave = tid >> 6, lane = tid & 63;
  const int l15 = lane & 15, lg = lane >> 4;
  const int bid = ((blockIdx.x & 7) << 5) | (blockIdx.x >> 3);   // XCD swizzle, 256 blocks
  const int bm = bid >> 3, bn = bid & 7;                          // 32 x 8
  const int m0 = bm * 256, n0 = bn * 128;
  const int wr = wave >> 1, wc = wave & 1;                        // 4 x 2 waves

  const f32x4 fz = {0.f, 0.f, 0.f, 0.f};
  f32x4 acc[4][4];
#pragma unroll
  for (int m = 0; m < 4; ++m)
#pragma unroll
    for (int n = 0; n < 4; ++n) acc[m][n] = fz;

  const char* srcA[4]; int dstA[4];
  const char* srcB[2]; int dstB[2];
#pragma unroll
  for (int j = 0; j < 4; ++j) {
    const int x = (j * 512 + tid) * 16;           // [0,32768)
    const int row = x >> 7, colb = x & 127;
    const int pc = colb ^ ((row & 7) << 4);
    srcA[j] = (const char*)A + (size_t)(m0 + row) * 2048 + pc;
    dstA[j] = x;
  }
#pragma unroll
  for (int j = 0; j < 2; ++j) {
    const int x = (j * 512 + tid) * 16;           // [0,16384)
    const int row = x >> 7, colb = x & 127;
    const int pc = colb ^ ((row & 7) << 4);
    srcB[j] = (const char*)Bt + (size_t)(n0 + row) * 2048 + pc;
    dstB[j] = x;
  }

#define STAGE_G(buf, T)                                                     \
  do {                                                                      \
    _Pragma("unroll") for (int j = 0; j < 4; ++j)                           \
      async_cp16(srcA[j] + (size_t)(T) * 128, (char*)As[buf] + dstA[j]);    \
    _Pragma("unroll") for (int j = 0; j < 2; ++j)                           \
      async_cp16(srcB[j] + (size_t)(T) * 128, (char*)Bs[buf] + dstB[j]);    \
  } while (0)

  STAGE_G(0, 0);
  STAGE_G(1, 1);
  asm volatile("s_waitcnt vmcnt(6)" ::: "memory");
  __builtin_amdgcn_s_barrier();
  __builtin_amdgcn_sched_barrier(0);

#define GEMM_IT(T, BR, BS, DOSTAGE, DOBAR, CNT)                             \
  do {                                                                      \
    if (DOSTAGE) STAGE_G(BS, (T) + 2);                                      \
    half8 af[2][4], bf[2][4];                                               \
    _Pragma("unroll") for (int kk = 0; kk < 2; ++kk)                        \
      _Pragma("unroll") for (int m = 0; m < 4; ++m) {                       \
        const int row = wr * 64 + m * 16 + l15;                             \
        af[kk][m] = *(const half8*)((const char*)As[BR] +                   \
            ((row * 128 + kk * 64 + lg * 16) ^ ((row & 7) << 4)));          \
      }                                                                     \
    _Pragma("unroll") for (int kk = 0; kk < 2; ++kk)                        \
      _Pragma("unroll") for (int n = 0; n < 4; ++n) {                       \
        const int row = wc * 64 + n * 16 + l15;                             \
        bf[kk][n] = *(const half8*)((const char*)Bs[BR] +                   \
            ((row * 128 + kk * 64 + lg * 16) ^ ((row & 7) << 4)));          \
      }                                                                     \
    _Pragma("unroll") for (int kk = 0; kk < 2; ++kk)                        \
      _Pragma("unroll") for (int m = 0; m < 4; ++m)                         \
        _Pragma("unroll") for (int n = 0; n < 4; ++n)                       \
          acc[m][n] = __builtin_amdgcn_mfma_f32_16x16x32_f16(af[kk][m], bf[kk][n], acc[m][n], 0, 0, 0); \
    if (DOBAR) {                                                            \
      if (CNT) asm volatile("s_waitcnt vmcnt(6)" ::: "memory");             \
      else     asm volatile("s_waitcnt vmcnt(0)" ::: "memory");             \
      __builtin_amdgcn_s_barrier();                                         \
      __builtin_amdgcn_sched_barrier(0);                                    \
    }                                                                       \
  } while (0)

  for (int tb = 0; tb < 12; tb += 3) {
    GEMM_IT(tb,     0, 2, 1, 1, 1);
    GEMM_IT(tb + 1, 1, 0, 1, 1, 1);
    GEMM_IT(tb + 2, 2, 1, 1, 1, 1);
  }
  GEMM_IT(12, 0, 2, 1, 1, 1);
  GEMM_IT(13, 1, 0, 1, 1, 1);
  GEMM_IT(14, 2, 1, 0, 1, 0);
  GEMM_IT(15, 0, 1, 0, 0, 0);
#undef GEMM_IT
#undef STAGE_G

  const float scl = (epi == 0) ? 0.18033688f : 1.0f;  // 0.125*log2e folded (exp2 domain)
#pragma unroll
  for (int m = 0; m < 4; ++m) {
    const int Rb = m0 + wr * 64 + m * 16 + lg * 4;
#pragma unroll
    for (int n = 0; n < 4; ++n) {
      const int C = n0 + wc * 64 + n * 16 + l15;
      const float bv = bias[C];
#pragma unroll
      for (int i = 0; i < 4; ++i) {
        const int R = Rb + i;
        const float vv = acc[m][n][i] + bv;
        if (epi == 3) {
          ((float*)outv)[(size_t)R * 1024 + C] = vv;
        } else {
          const int b = R >> 11, t = R & 2047, hh = C >> 6, d = C & 63;
          if (epi == 2)
            ((u16*)outv)[((b * 16 + hh) * 64 + d) * 2048 + t] = f2h_bits(vv);
          else
            ((u16*)outv)[((b * 16 + hh) * 2048 + t) * 64 + d] = f2h_bits(vv * scl);
        }
      }
    }
  }
}

struct QKVParams {
  const u16*   A[3];
  const u16*   Bt[3];
  const float* bias[3];
  u16*         out[3];
};

__launch_bounds__(512)
__global__ void gemm_qkv(QKVParams p)
{
  __shared__ u16 As[3][16384];   // 96KB
  __shared__ u16 Bs[3][8192];    // 48KB
  const int y = blockIdx.y;
  gemm_body(p.A[y], p.Bt[y], p.bias[y], y, p.out[y], As, Bs);
}

__launch_bounds__(512)
__global__ void gemm_o(const u16* __restrict__ A, const u16* __restrict__ Bt,
                       const float* __restrict__ bias, float* __restrict__ out)
{
  __shared__ u16 As[3][16384];
  __shared__ u16 Bs[3][8192];
  gemm_body(A, Bt, bias, 3, out, As, Bs);
}

// ---------------- flash attention v4 (unchanged from round 19/20) ----------------
__launch_bounds__(512)
__global__ void attn_kernel(const u16* __restrict__ qh, const u16* __restrict__ kh,
                            const u16* __restrict__ vt, u16* __restrict__ O)
{
  __shared__ u16 SM[32768];   // 64KB: K bufs [0,32KB), V bufs [32,64KB); Q prologue spans all
  const int tid = threadIdx.x, wave = tid >> 6, lane = tid & 63;
  const int l15 = lane & 15, lg = lane >> 4;
  const int swz = ((blockIdx.x & 7) << 5) | (blockIdx.x >> 3);   // XCD swizzle, [0,256)
  const int bh = swz >> 2;                 // b*16+h
  const int q0 = (swz & 3) << 9;           // 512 q-rows/block
  const int b = bh >> 4, h = bh & 15;

  const char* qbase = (const char*)(qh + (size_t)(bh * 2048 + q0) * 64);
  const char* kbase = (const char*)(kh + (size_t)bh * 2048 * 64);
  const char* vbase = (const char*)(vt + (size_t)bh * 64 * 2048);

  char* Kbuf[4] = { (char*)SM,         (char*)SM + 8192,
                    (char*)SM + 16384, (char*)SM + 24576 };
  char* Vbuf[4] = { (char*)SM + 32768, (char*)SM + 40960,
                    (char*)SM + 49152, (char*)SM + 57344 };

  const bool isK = wave < 4;
  const char* ksrc[2]; int kdst[2];
  const char* vsrc[2]; int vdstA[2], vdstB[2];
#pragma unroll
  for (int j = 0; j < 2; ++j) {
    if (isK) {
      const int yb = wave * 2048 + j * 1024 + lane * 16;   // [0,8192)
      const int row = yb >> 7;
      ksrc[j] = kbase + (yb ^ ((row & 7) << 4));
      kdst[j] = yb;
      vsrc[j] = nullptr; vdstA[j] = vdstB[j] = 0;
    } else {
      const int u = (wave - 4) * 128 + j * 64 + lane;      // [0,512)
      const int d = u >> 3, a = u & 7;
      vsrc[j] = vbase + (size_t)d * 4096 + a * 16;
      const int n = a >> 1;
      const int s1 = 32 * (n >> 1) + 16 * (a & 1) + 4 * (n & 1);
      const int sw = (d & 7) << 4;
      vdstA[j] = (d * 128 + 2 * s1) ^ sw;
      vdstB[j] = (d * 128 + 2 * s1 + 16) ^ sw;
      ksrc[j] = nullptr; kdst[j] = 0;
    }
  }

  // ---- prologue: Q (64KB = 512 rows x 128B) through SM; read 4 fragment groups ----
#pragma unroll
  for (int j = 0; j < 8; ++j) {
    const int x = j * 8192 + tid * 16;     // [0,65536)
    const int row = x >> 7;
    async_cp16(qbase + (x ^ ((row & 7) << 4)), (char*)SM + x);
  }
  __syncthreads();
  half8 aq[4][2];   // [G][k-half]
#pragma unroll
  for (int G = 0; G < 4; ++G) {
    const int qr = wave * 64 + G * 16 + l15;               // [0,512)
#pragma unroll
    for (int hh = 0; hh < 2; ++hh) {
      const int addr = (qr * 128 + hh * 64 + lg * 16) ^ ((qr & 7) << 4);
      aq[G][hh] = *(const half8*)((const char*)SM + addr);
    }
  }
  asm volatile("s_waitcnt lgkmcnt(0)" ::: "memory");
  __syncthreads();

  // ---- pipeline prologue: tiles 0,1 staged; va <- tiles 2,3 ----
  uint4 va[2][2];   // [tile parity within pair][j]
  if (isK) {
    async_cp16(ksrc[0], Kbuf[0] + kdst[0]);
    async_cp16(ksrc[1], Kbuf[0] + kdst[1]);
    async_cp16(ksrc[0] + 8192, Kbuf[1] + kdst[0]);
    async_cp16(ksrc[1] + 8192, Kbuf[1] + kdst[1]);
    asm volatile("s_waitcnt vmcnt(0)" ::: "memory");
  } else {
#pragma unroll
    for (int tt = 0; tt < 2; ++tt)
#pragma unroll
      for (int j = 0; j < 2; ++j) {
        uint4 v = *(const uint4*)(vsrc[j] + (size_t)tt * 128);
        uint2 w0; w0.x = v.x; w0.y = v.y;
        uint2 w1; w1.x = v.z; w1.y = v.w;
        *(uint2*)(Vbuf[tt] + vdstA[j]) = w0;
        *(uint2*)(Vbuf[tt] + vdstB[j]) = w1;
      }
#pragma unroll
    for (int j = 0; j < 2; ++j) {
      va[0][j] = *(const uint4*)(vsrc[j] + 2 * 128);
      va[1][j] = *(const uint4*)(vsrc[j] + 3 * 128);
    }
    asm volatile("s_waitcnt lgkmcnt(0)" ::: "memory");
  }
  __builtin_amdgcn_s_barrier();
  __builtin_amdgcn_sched_barrier(0);

  half8 ones;
#pragma unroll
  for (int i = 0; i < 8; ++i) ones[i] = (_Float16)1.0f;

  const f32x4 fz = {0.f, 0.f, 0.f, 0.f};
  f32x4 o[4][4], osum[4];
#pragma unroll
  for (int i = 0; i < 4; ++i) {
#pragma unroll
    for (int G = 0; G < 4; ++G) o[i][G] = fz;
    osum[i] = fz;
  }

#define ATTN_TILE(BT)                                                           \
  do {                                                                          \
    half8 pa[4][2];                                                             \
    _Pragma("unroll") for (int hp = 0; hp < 2; ++hp) {                          \
      f32x4 s0[4], s1[4];                                                       \
      __builtin_amdgcn_s_setprio(1);                                            \
      {                                                                         \
        const int krow = (2 * hp) * 16 + l15;                                   \
        const int a0 = (krow * 128 + lg * 16) ^ ((krow & 7) << 4);              \
        half8 bk0 = *(const half8*)(Kbuf[BT] + a0);                             \
        half8 bk1 = *(const half8*)(Kbuf[BT] + (a0 ^ 64));                      \
        _Pragma("unroll") for (int G = 0; G < 4; ++G) {                         \
          s0[G] = __builtin_amdgcn_mfma_f32_16x16x32_f16(bk0, aq[G][0], fz, 0, 0, 0); \
          s0[G] = __builtin_amdgcn_mfma_f32_16x16x32_f16(bk1, aq[G][1], s0[G], 0, 0, 0); \
        }                                                                       \
      }                                                                         \
      {                                                                         \
        const int krow = (2 * hp + 1) * 16 + l15;                               \
        const int a0 = (krow * 128 + lg * 16) ^ ((krow & 7) << 4);              \
        half8 bk0 = *(const half8*)(Kbuf[BT] + a0);                             \
        half8 bk1 = *(const half8*)(Kbuf[BT] + (a0 ^ 64));                      \
        _Pragma("unroll") for (int G = 0; G < 4; ++G) {                         \
          s1[G] = __builtin_amdgcn_mfma_f32_16x16x32_f16(bk0, aq[G][0], fz, 0, 0, 0); \
          s1[G] = __builtin_amdgcn_mfma_f32_16x16x32_f16(bk1, aq[G][1], s1[G], 0, 0, 0); \
        }                                                                       \
      }                                                                         \
      __builtin_amdgcn_s_setprio(0);                                            \
      _Pragma("unroll") for (int G = 0; G < 4; ++G) {                           \
        union { u32 w[4]; half8 hv; } cv;                                       \
        cv.w[0] = pack2h(EXP2(s0[G][0]), EXP2(s0[G][1]));                       \
        cv.w[1] = pack2h(EXP2(s0[G][2]), EXP2(s0[G][3]));                       \
        cv.w[2] = pack2h(EXP2(s1[G][0]), EXP2(s1[G][1]));                       \
        cv.w[3] = pack2h(EXP2(s1[G][2]), EXP2(s1[G][3]));                       \
        pa[G][hp] = cv.hv;                                                      \
      }                                                                         \
    }                                                                           \
    __builtin_amdgcn_s_setprio(1);                                              \
    _Pragma("unroll") for (int G = 0; G < 4; ++G) {                             \
      osum[G] = __builtin_amdgcn_mfma_f32_16x16x32_f16(pa[G][0], ones, osum[G], 0, 0, 0); \
      osum[G] = __builtin_amdgcn_mfma_f32_16x16x32_f16(pa[G][1], ones, osum[G], 0, 0, 0); \
    }                                                                           \
    _Pragma("unroll") for (int nd = 0; nd < 4; ++nd) {                          \
      const int dr = nd * 16 + l15;                                             \
      const int a0 = (dr * 128 + lg * 16) ^ ((dr & 7) << 4);                    \
      half8 bv0 = *(const half8*)(Vbuf[BT] + a0);                               \
      half8 bv1 = *(const half8*)(Vbuf[BT] + (a0 ^ 64));                        \
      _Pragma("unroll") for (int G = 0; G < 4; ++G) {                           \
        o[nd][G] = __builtin_amdgcn_mfma_f32_16x16x32_f16(pa[G][0], bv0, o[nd][G], 0, 0, 0); \
        o[nd][G] = __builtin_amdgcn_mfma_f32_16x16x32_f16(pa[G][1], bv1, o[nd][G], 0, 0, 0); \
      }                                                                         \
    }                                                                           \
    __builtin_amdgcn_s_setprio(0);                                              \
  } while (0)

#define PERIOD(P, C0, C1, S0, S1, DOSTAGE, DOVA, DOBAR)                         \
  do {                                                                          \
    if (isK) {                                                                  \
      if (DOSTAGE) {                                                            \
        async_cp16(ksrc[0] + (size_t)(2*(P)+2) * 8192, Kbuf[S0] + kdst[0]);     \
        async_cp16(ksrc[1] + (size_t)(2*(P)+2) * 8192, Kbuf[S0] + kdst[1]);     \
        async_cp16(ksrc[0] + (size_t)(2*(P)+3) * 8192, Kbuf[S1] + kdst[0]);     \
        async_cp16(ksrc[1] + (size_t)(2*(P)+3) * 8192, Kbuf[S1] + kdst[1]);     \
      }                                                                         \
    } else {                                                                    \
      if (DOSTAGE) {                                                            \
        _Pragma("unroll") for (int j = 0; j < 2; ++j) {                         \
          uint2 w0, w1;                                                         \
          w0.x = va[0][j].x; w0.y = va[0][j].y;                                 \
          w1.x = va[0][j].z; w1.y = va[0][j].w;                                 \
          *(uint2*)(Vbuf[S0] + vdstA[j]) = w0;                                  \
          *(uint2*)(Vbuf[S0] + vdstB[j]) = w1;                                  \
          w0.x = va[1][j].x; w0.y = va[1][j].y;                                 \
          w1.x = va[1][j].z; w1.y = va[1][j].w;                                 \
          *(uint2*)(Vbuf[S1] + vdstA[j]) = w0;                                  \
          *(uint2*)(Vbuf[S1] + vdstB[j]) = w1;                                  \
        }                                                                       \
        if (DOVA) {                                                             \
          _Pragma("unroll") for (int j = 0; j < 2; ++j) {                       \
            va[0][j] = *(const uint4*)(vsrc[j] + (size_t)(2*(P)+4) * 128);      \
            va[1][j] = *(const uint4*)(vsrc[j] + (size_t)(2*(P)+5) * 128);      \
          }                                                                     \
        }                                                                       \
      }                                                                         \
    }                                                                           \
    ATTN_TILE(C0);                                                              \
    ATTN_TILE(C1);                                                              \
    if (DOBAR) {                                                                \
      if (isK) asm volatile("s_waitcnt vmcnt(0)" ::: "memory");                 \
      else     asm volatile("s_waitcnt lgkmcnt(0)" ::: "memory");               \
      __builtin_amdgcn_s_barrier();                                             \
      __builtin_amdgcn_sched_barrier(0);                                        \
    }                                                                           \
  } while (0)

  for (int pb = 0; pb < 14; pb += 2) {
    PERIOD(pb,     0, 1, 2, 3, 1, 1, 1);
    PERIOD(pb + 1, 2, 3, 0, 1, 1, 1, 1);
  }
  PERIOD(14, 0, 1, 2, 3, 1, 0, 1);
  PERIOD(15, 2, 3, 0, 1, 0, 0, 0);
#undef PERIOD
#undef ATTN_TILE

#pragma unroll
  for (int G = 0; G < 4; ++G)
#pragma unroll
    for (int i = 0; i < 4; ++i) {
      const float inv = 1.f / osum[G][i];
      const int t = q0 + wave * 64 + G * 16 + lg * 4 + i;
      u16* orow = O + ((size_t)(b * 2048 + t)) * 1024 + h * 64;
#pragma unroll
      for (int nd = 0; nd < 4; ++nd)
        orow[nd * 16 + l15] = f2h_bits(o[nd][G][i] * inv);
    }
}

extern "C" void kernel_launch(void* const* d_in, const int* in_sizes, int n_in,
                              void* d_out, int out_size, void* d_ws, size_t ws_size,
                              hipStream_t stream)
{
  const float* q  = (const float*)d_in[0];
  const float* k  = (const float*)d_in[1];
  const float* v  = (const float*)d_in[2];
  const float* Wq = (const float*)d_in[3];
  const float* bq = (const float*)d_in[4];
  const float* Wk = (const float*)d_in[5];
  const float* bk = (const float*)d_in[6];
  const float* Wv = (const float*)d_in[7];
  const float* bv = (const float*)d_in[8];
  const float* Wo = (const float*)d_in[9];
  const float* bo = (const float*)d_in[10];

  u16* W = (u16*)d_ws;
  const unsigned MB = 1u << 20;   // element (u16) units
  u16* wtq = W + 0 * MB;
  u16* wtk = W + 1 * MB;
  u16* wtv = W + 2 * MB;
  u16* wto = W + 3 * MB;
  u16* qhb = W + 4 * MB;
  u16* khb = W + 12 * MB;
  u16* vtb = W + 20 * MB;
  u16* Xb  = W + 28 * MB;   // xq (cvt) then attention output
  u16* xk  = W + 36 * MB;
  u16* xv  = W + 44 * MB;

  TParams tp;
  tp.W[0] = Wq; tp.W[1] = Wk; tp.W[2] = Wv; tp.W[3] = Wo;
  tp.out[0] = wtq; tp.out[1] = wtk; tp.out[2] = wtv; tp.out[3] = wto;
  tcvt4<<<4096, 256, 0, stream>>>(tp);

  CParams cp;
  cp.in[0] = (const float4*)q; cp.in[1] = (const float4*)k; cp.in[2] = (const float4*)v;
  cp.out[0] = Xb; cp.out[1] = xk; cp.out[2] = xv;
  cvt3<<<24576, 256, 0, stream>>>(cp);

  QKVParams qp;
  qp.A[0] = Xb;  qp.A[1] = xk;  qp.A[2] = xv;
  qp.Bt[0] = wtq; qp.Bt[1] = wtk; qp.Bt[2] = wtv;
  qp.bias[0] = bq; qp.bias[1] = bk; qp.bias[2] = bv;
  qp.out[0] = qhb; qp.out[1] = khb; qp.out[2] = vtb;
  gemm_qkv<<<dim3(256, 3), 512, 0, stream>>>(qp);

  attn_kernel<<<256, 512, 0, stream>>>(qhb, khb, vtb, Xb);

  gemm_o<<<256, 512, 0, stream>>>(Xb, wto, bo, (float*)d_out);
}

// Round 22
// 199.127 us; speedup vs baseline: 1.0992x; 1.0992x over previous
//
#include <hip/hip_runtime.h>
#include <cstdint>

#define DEV static __device__ __forceinline__

typedef unsigned short u16;
typedef unsigned int u32;
typedef __attribute__((ext_vector_type(8))) _Float16 half8;
typedef __attribute__((ext_vector_type(4))) float f32x4;
typedef __attribute__((ext_vector_type(4))) unsigned short u16x4;

DEV u16 f2h_bits(float f) {
  _Float16 h = (_Float16)f;
  union { _Float16 h; u16 u; } cv; cv.h = h; return cv.u;
}

DEV u32 pack2h(float a, float b) {
  union { __fp16 __attribute__((ext_vector_type(2))) h; u32 u; } cv;
  cv.h = __builtin_amdgcn_cvt_pkrtz(a, b);
  return cv.u;
}

#define EXP2 __builtin_amdgcn_exp2f   // raw v_exp_f32 (exp2f = ~10 instr via OCML)

DEV void async_cp16(const void* g, void* l) {
  __builtin_amdgcn_global_load_lds(
      (const __attribute__((address_space(1))) void*)g,
      (__attribute__((address_space(3))) void*)l, 16, 0, 0);
}

// ---------------- 3x fused fp32 -> fp16 convert (one streaming launch) ----------------
struct CParams { const float4* in[3]; u16* out[3]; };

__global__ void cvt3(CParams p) {
  const int w = blockIdx.x >> 13;                  // 8192 blocks per tensor
  const int i = (blockIdx.x & 8191) * 256 + threadIdx.x;
  float4 f = p.in[w][i];
  u16x4 u;
  u.x = f2h_bits(f.x); u.y = f2h_bits(f.y); u.z = f2h_bits(f.z); u.w = f2h_bits(f.w);
  *(u16x4*)(p.out[w] + i * 4) = u;
}

// ---------------- 4x fused W [K][N] fp32 -> Wt [N][K] fp16 ----------------
struct TParams { const float* W[4]; u16* out[4]; };

__global__ void tcvt4(TParams p) {
  __shared__ float tile[32][33];
  const int w = blockIdx.x >> 10;
  const int bidx = blockIdx.x & 1023;
  const float* __restrict__ Wf = p.W[w];
  u16* __restrict__ Wt = p.out[w];
  const int bx = bidx & 31, by = bidx >> 5;
  const int tx = threadIdx.x & 31, ty = threadIdx.x >> 5;
#pragma unroll
  for (int r = 0; r < 32; r += 8)
    tile[ty + r][tx] = Wf[(by * 32 + ty + r) * 1024 + bx * 32 + tx];
  __syncthreads();
#pragma unroll
  for (int r = 0; r < 32; r += 8)
    Wt[(bx * 32 + ty + r) * 1024 + by * 32 + tx] = f2h_bits(tile[tx][ty + r]);
}

// ======== GEMM v3: 256x128 tile, 8 waves, BK=64, 3-buffer counted vmcnt(6) ========
// C[8192,1024] = A_f16 * Bt_f16^T (+bias per EPI); grid 256 = 1 block/CU.
// EPI 0: qh fp16 *0.125*log2e  1: kh fp16  2: vt fp16 transposed  3: f32 row-major
template<int EPI, typename OutT>
DEV void gemm_body(const u16* __restrict__ A, const u16* __restrict__ Bt,
                   const float* __restrict__ bias, OutT* __restrict__ out,
                   u16 (*As)[16384], u16 (*Bs)[8192])
{
  const int tid = threadIdx.x;
  const int wave = tid >> 6, lane = tid & 63;
  const int l15 = lane & 15, lg = lane >> 4;
  const int bid = ((blockIdx.x & 7) << 5) | (blockIdx.x >> 3);   // XCD swizzle, 256 blocks
  const int bm = bid >> 3, bn = bid & 7;                          // 32 x 8
  const int m0 = bm * 256, n0 = bn * 128;
  const int wr = wave >> 1, wc = wave & 1;                        // 4 x 2 waves

  const f32x4 fz = {0.f, 0.f, 0.f, 0.f};
  f32x4 acc[4][4];
#pragma unroll
  for (int m = 0; m < 4; ++m)
#pragma unroll
    for (int n = 0; n < 4; ++n) acc[m][n] = fz;

  // A tile 256x64 (32KB): 4 chunks/thread. B tile 128x64 (16KB): 2 chunks/thread.
  const char* srcA[4]; int dstA[4];
  const char* srcB[2]; int dstB[2];
#pragma unroll
  for (int j = 0; j < 4; ++j) {
    const int x = (j * 512 + tid) * 16;           // [0,32768)
    const int row = x >> 7, colb = x & 127;
    const int pc = colb ^ ((row & 7) << 4);
    srcA[j] = (const char*)A + (size_t)(m0 + row) * 2048 + pc;
    dstA[j] = x;
  }
#pragma unroll
  for (int j = 0; j < 2; ++j) {
    const int x = (j * 512 + tid) * 16;           // [0,16384)
    const int row = x >> 7, colb = x & 127;
    const int pc = colb ^ ((row & 7) << 4);
    srcB[j] = (const char*)Bt + (size_t)(n0 + row) * 2048 + pc;
    dstB[j] = x;
  }

#define STAGE_G(buf, T)                                                     \
  do {                                                                      \
    _Pragma("unroll") for (int j = 0; j < 4; ++j)                           \
      async_cp16(srcA[j] + (size_t)(T) * 128, (char*)As[buf] + dstA[j]);    \
    _Pragma("unroll") for (int j = 0; j < 2; ++j)                           \
      async_cp16(srcB[j] + (size_t)(T) * 128, (char*)Bs[buf] + dstB[j]);    \
  } while (0)

  STAGE_G(0, 0);
  STAGE_G(1, 1);
  asm volatile("s_waitcnt vmcnt(6)" ::: "memory");
  __builtin_amdgcn_s_barrier();
  __builtin_amdgcn_sched_barrier(0);

#define GEMM_IT(T, BR, BS, DOSTAGE, DOBAR, CNT)                             \
  do {                                                                      \
    if (DOSTAGE) STAGE_G(BS, (T) + 2);                                      \
    half8 af[2][4], bf[2][4];                                               \
    _Pragma("unroll") for (int kk = 0; kk < 2; ++kk)                        \
      _Pragma("unroll") for (int m = 0; m < 4; ++m) {                       \
        const int row = wr * 64 + m * 16 + l15;                             \
        af[kk][m] = *(const half8*)((const char*)As[BR] +                   \
            ((row * 128 + kk * 64 + lg * 16) ^ ((row & 7) << 4)));          \
      }                                                                     \
    _Pragma("unroll") for (int kk = 0; kk < 2; ++kk)                        \
      _Pragma("unroll") for (int n = 0; n < 4; ++n) {                       \
        const int row = wc * 64 + n * 16 + l15;                             \
        bf[kk][n] = *(const half8*)((const char*)Bs[BR] +                   \
            ((row * 128 + kk * 64 + lg * 16) ^ ((row & 7) << 4)));          \
      }                                                                     \
    _Pragma("unroll") for (int kk = 0; kk < 2; ++kk)                        \
      _Pragma("unroll") for (int m = 0; m < 4; ++m)                         \
        _Pragma("unroll") for (int n = 0; n < 4; ++n)                       \
          acc[m][n] = __builtin_amdgcn_mfma_f32_16x16x32_f16(af[kk][m], bf[kk][n], acc[m][n], 0, 0, 0); \
    if (DOBAR) {                                                            \
      if (CNT) asm volatile("s_waitcnt vmcnt(6)" ::: "memory");             \
      else     asm volatile("s_waitcnt vmcnt(0)" ::: "memory");             \
      __builtin_amdgcn_s_barrier();                                         \
      __builtin_amdgcn_sched_barrier(0);                                    \
    }                                                                       \
  } while (0)

  for (int tb = 0; tb < 12; tb += 3) {
    GEMM_IT(tb,     0, 2, 1, 1, 1);
    GEMM_IT(tb + 1, 1, 0, 1, 1, 1);
    GEMM_IT(tb + 2, 2, 1, 1, 1, 1);
  }
  GEMM_IT(12, 0, 2, 1, 1, 1);
  GEMM_IT(13, 1, 0, 1, 1, 1);
  GEMM_IT(14, 2, 1, 0, 1, 0);   // drain tile 15 fully
  GEMM_IT(15, 0, 1, 0, 0, 0);
#undef GEMM_IT
#undef STAGE_G

#pragma unroll
  for (int m = 0; m < 4; ++m) {
    const int Rb = m0 + wr * 64 + m * 16 + lg * 4;
#pragma unroll
    for (int n = 0; n < 4; ++n) {
      const int C = n0 + wc * 64 + n * 16 + l15;
      const float bv = bias[C];
#pragma unroll
      for (int i = 0; i < 4; ++i) {
        const int R = Rb + i;
        const float vv = acc[m][n][i] + bv;
        if (EPI == 3) {
          ((float*)out)[(size_t)R * 1024 + C] = vv;
        } else {
          const int b = R >> 11, t = R & 2047, hh = C >> 6, d = C & 63;
          if (EPI == 0)
            ((u16*)out)[((b * 16 + hh) * 2048 + t) * 64 + d] = f2h_bits(vv * 0.18033688f);
          else if (EPI == 1)
            ((u16*)out)[((b * 16 + hh) * 2048 + t) * 64 + d] = f2h_bits(vv);
          else
            ((u16*)out)[((b * 16 + hh) * 64 + d) * 2048 + t] = f2h_bits(vv);
        }
      }
    }
  }
}

template<int EPI>
__launch_bounds__(512)
__global__ void gemm_proj(const u16* __restrict__ A, const u16* __restrict__ Bt,
                          const float* __restrict__ bias, u16* __restrict__ out)
{
  __shared__ u16 As[3][16384];   // 96KB
  __shared__ u16 Bs[3][8192];    // 48KB
  gemm_body<EPI, u16>(A, Bt, bias, out, As, Bs);
}

__launch_bounds__(512)
__global__ void gemm_o(const u16* __restrict__ A, const u16* __restrict__ Bt,
                       const float* __restrict__ bias, float* __restrict__ out)
{
  __shared__ u16 As[3][16384];
  __shared__ u16 Bs[3][8192];
  gemm_body<3, float>(A, Bt, bias, out, As, Bs);
}

// ---------------- flash attention v4 (unchanged from rounds 19-21) ----------------
__launch_bounds__(512)
__global__ void attn_kernel(const u16* __restrict__ qh, const u16* __restrict__ kh,
                            const u16* __restrict__ vt, u16* __restrict__ O)
{
  __shared__ u16 SM[32768];   // 64KB: K bufs [0,32KB), V bufs [32,64KB); Q prologue spans all
  const int tid = threadIdx.x, wave = tid >> 6, lane = tid & 63;
  const int l15 = lane & 15, lg = lane >> 4;
  const int swz = ((blockIdx.x & 7) << 5) | (blockIdx.x >> 3);   // XCD swizzle, [0,256)
  const int bh = swz >> 2;                 // b*16+h
  const int q0 = (swz & 3) << 9;           // 512 q-rows/block
  const int b = bh >> 4, h = bh & 15;

  const char* qbase = (const char*)(qh + (size_t)(bh * 2048 + q0) * 64);
  const char* kbase = (const char*)(kh + (size_t)bh * 2048 * 64);
  const char* vbase = (const char*)(vt + (size_t)bh * 64 * 2048);

  char* Kbuf[4] = { (char*)SM,         (char*)SM + 8192,
                    (char*)SM + 16384, (char*)SM + 24576 };
  char* Vbuf[4] = { (char*)SM + 32768, (char*)SM + 40960,
                    (char*)SM + 49152, (char*)SM + 57344 };

  const bool isK = wave < 4;
  const char* ksrc[2]; int kdst[2];
  const char* vsrc[2]; int vdstA[2], vdstB[2];
#pragma unroll
  for (int j = 0; j < 2; ++j) {
    if (isK) {
      const int yb = wave * 2048 + j * 1024 + lane * 16;   // [0,8192)
      const int row = yb >> 7;
      ksrc[j] = kbase + (yb ^ ((row & 7) << 4));
      kdst[j] = yb;
      vsrc[j] = nullptr; vdstA[j] = vdstB[j] = 0;
    } else {
      const int u = (wave - 4) * 128 + j * 64 + lane;      // [0,512)
      const int d = u >> 3, a = u & 7;
      vsrc[j] = vbase + (size_t)d * 4096 + a * 16;
      const int n = a >> 1;
      const int s1 = 32 * (n >> 1) + 16 * (a & 1) + 4 * (n & 1);
      const int sw = (d & 7) << 4;
      vdstA[j] = (d * 128 + 2 * s1) ^ sw;
      vdstB[j] = (d * 128 + 2 * s1 + 16) ^ sw;
      ksrc[j] = nullptr; kdst[j] = 0;
    }
  }

  // ---- prologue: Q (64KB = 512 rows x 128B) through SM; read 4 fragment groups ----
#pragma unroll
  for (int j = 0; j < 8; ++j) {
    const int x = j * 8192 + tid * 16;     // [0,65536)
    const int row = x >> 7;
    async_cp16(qbase + (x ^ ((row & 7) << 4)), (char*)SM + x);
  }
  __syncthreads();
  half8 aq[4][2];   // [G][k-half]
#pragma unroll
  for (int G = 0; G < 4; ++G) {
    const int qr = wave * 64 + G * 16 + l15;               // [0,512)
#pragma unroll
    for (int hh = 0; hh < 2; ++hh) {
      const int addr = (qr * 128 + hh * 64 + lg * 16) ^ ((qr & 7) << 4);
      aq[G][hh] = *(const half8*)((const char*)SM + addr);
    }
  }
  asm volatile("s_waitcnt lgkmcnt(0)" ::: "memory");
  __syncthreads();

  // ---- pipeline prologue: tiles 0,1 staged; va <- tiles 2,3 ----
  uint4 va[2][2];   // [tile parity within pair][j]
  if (isK) {
    async_cp16(ksrc[0], Kbuf[0] + kdst[0]);
    async_cp16(ksrc[1], Kbuf[0] + kdst[1]);
    async_cp16(ksrc[0] + 8192, Kbuf[1] + kdst[0]);
    async_cp16(ksrc[1] + 8192, Kbuf[1] + kdst[1]);
    asm volatile("s_waitcnt vmcnt(0)" ::: "memory");
  } else {
#pragma unroll
    for (int tt = 0; tt < 2; ++tt)
#pragma unroll
      for (int j = 0; j < 2; ++j) {
        uint4 v = *(const uint4*)(vsrc[j] + (size_t)tt * 128);
        uint2 w0; w0.x = v.x; w0.y = v.y;
        uint2 w1; w1.x = v.z; w1.y = v.w;
        *(uint2*)(Vbuf[tt] + vdstA[j]) = w0;
        *(uint2*)(Vbuf[tt] + vdstB[j]) = w1;
      }
#pragma unroll
    for (int j = 0; j < 2; ++j) {
      va[0][j] = *(const uint4*)(vsrc[j] + 2 * 128);
      va[1][j] = *(const uint4*)(vsrc[j] + 3 * 128);
    }
    asm volatile("s_waitcnt lgkmcnt(0)" ::: "memory");
  }
  __builtin_amdgcn_s_barrier();
  __builtin_amdgcn_sched_barrier(0);

  half8 ones;
#pragma unroll
  for (int i = 0; i < 8; ++i) ones[i] = (_Float16)1.0f;

  const f32x4 fz = {0.f, 0.f, 0.f, 0.f};
  f32x4 o[4][4], osum[4];
#pragma unroll
  for (int i = 0; i < 4; ++i) {
#pragma unroll
    for (int G = 0; G < 4; ++G) o[i][G] = fz;
    osum[i] = fz;
  }

#define ATTN_TILE(BT)                                                           \
  do {                                                                          \
    half8 pa[4][2];                                                             \
    _Pragma("unroll") for (int hp = 0; hp < 2; ++hp) {                          \
      f32x4 s0[4], s1[4];                                                       \
      __builtin_amdgcn_s_setprio(1);                                            \
      {                                                                         \
        const int krow = (2 * hp) * 16 + l15;                                   \
        const int a0 = (krow * 128 + lg * 16) ^ ((krow & 7) << 4);              \
        half8 bk0 = *(const half8*)(Kbuf[BT] + a0);                             \
        half8 bk1 = *(const half8*)(Kbuf[BT] + (a0 ^ 64));                      \
        _Pragma("unroll") for (int G = 0; G < 4; ++G) {                         \
          s0[G] = __builtin_amdgcn_mfma_f32_16x16x32_f16(bk0, aq[G][0], fz, 0, 0, 0); \
          s0[G] = __builtin_amdgcn_mfma_f32_16x16x32_f16(bk1, aq[G][1], s0[G], 0, 0, 0); \
        }                                                                       \
      }                                                                         \
      {                                                                         \
        const int krow = (2 * hp + 1) * 16 + l15;                               \
        const int a0 = (krow * 128 + lg * 16) ^ ((krow & 7) << 4);              \
        half8 bk0 = *(const half8*)(Kbuf[BT] + a0);                             \
        half8 bk1 = *(const half8*)(Kbuf[BT] + (a0 ^ 64));                      \
        _Pragma("unroll") for (int G = 0; G < 4; ++G) {                         \
          s1[G] = __builtin_amdgcn_mfma_f32_16x16x32_f16(bk0, aq[G][0], fz, 0, 0, 0); \
          s1[G] = __builtin_amdgcn_mfma_f32_16x16x32_f16(bk1, aq[G][1], s1[G], 0, 0, 0); \
        }                                                                       \
      }                                                                         \
      __builtin_amdgcn_s_setprio(0);                                            \
      _Pragma("unroll") for (int G = 0; G < 4; ++G) {                           \
        union { u32 w[4]; half8 hv; } cv;                                       \
        cv.w[0] = pack2h(EXP2(s0[G][0]), EXP2(s0[G][1]));                       \
        cv.w[1] = pack2h(EXP2(s0[G][2]), EXP2(s0[G][3]));                       \
        cv.w[2] = pack2h(EXP2(s1[G][0]), EXP2(s1[G][1]));                       \
        cv.w[3] = pack2h(EXP2(s1[G][2]), EXP2(s1[G][3]));                       \
        pa[G][hp] = cv.hv;                                                      \
      }                                                                         \
    }                                                                           \
    __builtin_amdgcn_s_setprio(1);                                              \
    _Pragma("unroll") for (int G = 0; G < 4; ++G) {                             \
      osum[G] = __builtin_amdgcn_mfma_f32_16x16x32_f16(pa[G][0], ones, osum[G], 0, 0, 0); \
      osum[G] = __builtin_amdgcn_mfma_f32_16x16x32_f16(pa[G][1], ones, osum[G], 0, 0, 0); \
    }                                                                           \
    _Pragma("unroll") for (int nd = 0; nd < 4; ++nd) {                          \
      const int dr = nd * 16 + l15;                                             \
      const int a0 = (dr * 128 + lg * 16) ^ ((dr & 7) << 4);                    \
      half8 bv0 = *(const half8*)(Vbuf[BT] + a0);                               \
      half8 bv1 = *(const half8*)(Vbuf[BT] + (a0 ^ 64));                        \
      _Pragma("unroll") for (int G = 0; G < 4; ++G) {                           \
        o[nd][G] = __builtin_amdgcn_mfma_f32_16x16x32_f16(pa[G][0], bv0, o[nd][G], 0, 0, 0); \
        o[nd][G] = __builtin_amdgcn_mfma_f32_16x16x32_f16(pa[G][1], bv1, o[nd][G], 0, 0, 0); \
      }                                                                         \
    }                                                                           \
    __builtin_amdgcn_s_setprio(0);                                              \
  } while (0)

#define PERIOD(P, C0, C1, S0, S1, DOSTAGE, DOVA, DOBAR)                         \
  do {                                                                          \
    if (isK) {                                                                  \
      if (DOSTAGE) {                                                            \
        async_cp16(ksrc[0] + (size_t)(2*(P)+2) * 8192, Kbuf[S0] + kdst[0]);     \
        async_cp16(ksrc[1] + (size_t)(2*(P)+2) * 8192, Kbuf[S0] + kdst[1]);     \
        async_cp16(ksrc[0] + (size_t)(2*(P)+3) * 8192, Kbuf[S1] + kdst[0]);     \
        async_cp16(ksrc[1] + (size_t)(2*(P)+3) * 8192, Kbuf[S1] + kdst[1]);     \
      }                                                                         \
    } else {                                                                    \
      if (DOSTAGE) {                                                            \
        _Pragma("unroll") for (int j = 0; j < 2; ++j) {                         \
          uint2 w0, w1;                                                         \
          w0.x = va[0][j].x; w0.y = va[0][j].y;                                 \
          w1.x = va[0][j].z; w1.y = va[0][j].w;                                 \
          *(uint2*)(Vbuf[S0] + vdstA[j]) = w0;                                  \
          *(uint2*)(Vbuf[S0] + vdstB[j]) = w1;                                  \
          w0.x = va[1][j].x; w0.y = va[1][j].y;                                 \
          w1.x = va[1][j].z; w1.y = va[1][j].w;                                 \
          *(uint2*)(Vbuf[S1] + vdstA[j]) = w0;                                  \
          *(uint2*)(Vbuf[S1] + vdstB[j]) = w1;                                  \
        }                                                                       \
        if (DOVA) {                                                             \
          _Pragma("unroll") for (int j = 0; j < 2; ++j) {                       \
            va[0][j] = *(const uint4*)(vsrc[j] + (size_t)(2*(P)+4) * 128);      \
            va[1][j] = *(const uint4*)(vsrc[j] + (size_t)(2*(P)+5) * 128);      \
          }                                                                     \
        }                                                                       \
      }                                                                         \
    }                                                                           \
    ATTN_TILE(C0);                                                              \
    ATTN_TILE(C1);                                                              \
    if (DOBAR) {                                                                \
      if (isK) asm volatile("s_waitcnt vmcnt(0)" ::: "memory");                 \
      else     asm volatile("s_waitcnt lgkmcnt(0)" ::: "memory");               \
      __builtin_amdgcn_s_barrier();                                             \
      __builtin_amdgcn_sched_barrier(0);                                        \
    }                                                                           \
  } while (0)

  for (int pb = 0; pb < 14; pb += 2) {
    PERIOD(pb,     0, 1, 2, 3, 1, 1, 1);
    PERIOD(pb + 1, 2, 3, 0, 1, 1, 1, 1);
  }
  PERIOD(14, 0, 1, 2, 3, 1, 0, 1);
  PERIOD(15, 2, 3, 0, 1, 0, 0, 0);
#undef PERIOD
#undef ATTN_TILE

#pragma unroll
  for (int G = 0; G < 4; ++G)
#pragma unroll
    for (int i = 0; i < 4; ++i) {
      const float inv = 1.f / osum[G][i];
      const int t = q0 + wave * 64 + G * 16 + lg * 4 + i;
      u16* orow = O + ((size_t)(b * 2048 + t)) * 1024 + h * 64;
#pragma unroll
      for (int nd = 0; nd < 4; ++nd)
        orow[nd * 16 + l15] = f2h_bits(o[nd][G][i] * inv);
    }
}

extern "C" void kernel_launch(void* const* d_in, const int* in_sizes, int n_in,
                              void* d_out, int out_size, void* d_ws, size_t ws_size,
                              hipStream_t stream)
{
  const float* q  = (const float*)d_in[0];
  const float* k  = (const float*)d_in[1];
  const float* v  = (const float*)d_in[2];
  const float* Wq = (const float*)d_in[3];
  const float* bq = (const float*)d_in[4];
  const float* Wk = (const float*)d_in[5];
  const float* bk = (const float*)d_in[6];
  const float* Wv = (const float*)d_in[7];
  const float* bv = (const float*)d_in[8];
  const float* Wo = (const float*)d_in[9];
  const float* bo = (const float*)d_in[10];

  u16* W = (u16*)d_ws;
  const unsigned MB = 1u << 20;   // element (u16) units
  u16* wtq = W + 0 * MB;
  u16* wtk = W + 1 * MB;
  u16* wtv = W + 2 * MB;
  u16* wto = W + 3 * MB;
  u16* qhb = W + 4 * MB;
  u16* khb = W + 12 * MB;
  u16* vtb = W + 20 * MB;
  u16* Xb  = W + 28 * MB;   // xq (cvt) then attention output
  u16* xk  = W + 36 * MB;
  u16* xv  = W + 44 * MB;

  TParams tp;
  tp.W[0] = Wq; tp.W[1] = Wk; tp.W[2] = Wv; tp.W[3] = Wo;
  tp.out[0] = wtq; tp.out[1] = wtk; tp.out[2] = wtv; tp.out[3] = wto;
  tcvt4<<<4096, 256, 0, stream>>>(tp);

  CParams cp;
  cp.in[0] = (const float4*)q; cp.in[1] = (const float4*)k; cp.in[2] = (const float4*)v;
  cp.out[0] = Xb; cp.out[1] = xk; cp.out[2] = xv;
  cvt3<<<24576, 256, 0, stream>>>(cp);

  gemm_proj<0><<<256, 512, 0, stream>>>(Xb, wtq, bq, qhb);
  gemm_proj<1><<<256, 512, 0, stream>>>(xk, wtk, bk, khb);
  gemm_proj<2><<<256, 512, 0, stream>>>(xv, wtv, bv, vtb);

  attn_kernel<<<256, 512, 0, stream>>>(qhb, khb, vtb, Xb);

  gemm_o<<<256, 512, 0, stream>>>(Xb, wto, bo, (float*)d_out);
}

// Round 23
// 192.920 us; speedup vs baseline: 1.1346x; 1.0322x over previous
//
#include <hip/hip_runtime.h>
#include <cstdint>

#define DEV static __device__ __forceinline__

typedef unsigned short u16;
typedef unsigned int u32;
typedef __attribute__((ext_vector_type(8))) _Float16 half8;
typedef __attribute__((ext_vector_type(4))) float f32x4;
typedef __attribute__((ext_vector_type(4))) unsigned short u16x4;

DEV u16 f2h_bits(float f) {
  _Float16 h = (_Float16)f;
  union { _Float16 h; u16 u; } cv; cv.h = h; return cv.u;
}

DEV u32 pack2h(float a, float b) {
  union { __fp16 __attribute__((ext_vector_type(2))) h; u32 u; } cv;
  cv.h = __builtin_amdgcn_cvt_pkrtz(a, b);
  return cv.u;
}

#define EXP2 __builtin_amdgcn_exp2f   // raw v_exp_f32 (exp2f = ~10 instr via OCML)

DEV void async_cp16(const void* g, void* l) {
  __builtin_amdgcn_global_load_lds(
      (const __attribute__((address_space(1))) void*)g,
      (__attribute__((address_space(3))) void*)l, 16, 0, 0);
}

// ---------------- prep: 4x weight transpose+cvt AND 3x activation cvt, one launch ----------------
struct PParams {
  const float* W[4];  u16* Wt[4];     // blocks [0,4096)
  const float4* in[3]; u16* out[3];   // blocks [4096, 28672)
};

__global__ void prep(PParams p) {
  __shared__ float tile[32][33];
  if (blockIdx.x < 4096) {
    const int w = blockIdx.x >> 10;
    const int bidx = blockIdx.x & 1023;
    const float* __restrict__ Wf = p.W[w];
    u16* __restrict__ Wt = p.Wt[w];
    const int bx = bidx & 31, by = bidx >> 5;
    const int tx = threadIdx.x & 31, ty = threadIdx.x >> 5;
#pragma unroll
    for (int r = 0; r < 32; r += 8)
      tile[ty + r][tx] = Wf[(by * 32 + ty + r) * 1024 + bx * 32 + tx];
    __syncthreads();
#pragma unroll
    for (int r = 0; r < 32; r += 8)
      Wt[(bx * 32 + ty + r) * 1024 + by * 32 + tx] = f2h_bits(tile[tx][ty + r]);
  } else {
    const int blk = blockIdx.x - 4096;
    const int w = blk >> 13;                  // 8192 blocks per tensor
    const int i = (blk & 8191) * 256 + threadIdx.x;
    float4 f = p.in[w][i];
    u16x4 u;
    u.x = f2h_bits(f.x); u.y = f2h_bits(f.y); u.z = f2h_bits(f.z); u.w = f2h_bits(f.w);
    *(u16x4*)(p.out[w] + i * 4) = u;
  }
}

// ======== GEMM v3.1: 256x128 tile, 8 waves, BK=64, 3-buffer counted vmcnt(6) ========
// Fragment LDS offsets precomputed (loop-invariant) -> ds_read with folded immediates.
// EPI 0: qh fp16 *0.125*log2e  1: kh fp16  2: vt fp16 transposed  3: f32 row-major
template<int EPI, typename OutT>
DEV void gemm_body(const u16* __restrict__ A, const u16* __restrict__ Bt,
                   const float* __restrict__ bias, OutT* __restrict__ out,
                   char* AsB, char* BsB)   // flat LDS bases: As 3x32768, Bs 3x16384
{
  const int tid = threadIdx.x;
  const int wave = tid >> 6, lane = tid & 63;
  const int l15 = lane & 15, lg = lane >> 4;
  const int bid = ((blockIdx.x & 7) << 5) | (blockIdx.x >> 3);   // XCD swizzle, 256 blocks
  const int bm = bid >> 3, bn = bid & 7;
  const int m0 = bm * 256, n0 = bn * 128;
  const int wr = wave >> 1, wc = wave & 1;

  const f32x4 fz = {0.f, 0.f, 0.f, 0.f};
  f32x4 acc[4][4];
#pragma unroll
  for (int m = 0; m < 4; ++m)
#pragma unroll
    for (int n = 0; n < 4; ++n) acc[m][n] = fz;

  // precomputed fragment offsets (loop-invariant)
  int abo[2][4], bbo[2][4];
#pragma unroll
  for (int kk = 0; kk < 2; ++kk) {
#pragma unroll
    for (int m = 0; m < 4; ++m) {
      const int row = wr * 64 + m * 16 + l15;
      abo[kk][m] = (row * 128 + kk * 64 + lg * 16) ^ ((row & 7) << 4);
    }
#pragma unroll
    for (int n = 0; n < 4; ++n) {
      const int row = wc * 64 + n * 16 + l15;
      bbo[kk][n] = (row * 128 + kk * 64 + lg * 16) ^ ((row & 7) << 4);
    }
  }

  const char* srcA[4]; int dstA[4];
  const char* srcB[2]; int dstB[2];
#pragma unroll
  for (int j = 0; j < 4; ++j) {
    const int x = (j * 512 + tid) * 16;           // [0,32768)
    const int row = x >> 7, colb = x & 127;
    const int pc = colb ^ ((row & 7) << 4);
    srcA[j] = (const char*)A + (size_t)(m0 + row) * 2048 + pc;
    dstA[j] = x;
  }
#pragma unroll
  for (int j = 0; j < 2; ++j) {
    const int x = (j * 512 + tid) * 16;           // [0,16384)
    const int row = x >> 7, colb = x & 127;
    const int pc = colb ^ ((row & 7) << 4);
    srcB[j] = (const char*)Bt + (size_t)(n0 + row) * 2048 + pc;
    dstB[j] = x;
  }

#define STAGE_G(buf, T)                                                       \
  do {                                                                        \
    _Pragma("unroll") for (int j = 0; j < 4; ++j)                             \
      async_cp16(srcA[j] + (size_t)(T) * 128, AsB + (buf) * 32768 + dstA[j]); \
    _Pragma("unroll") for (int j = 0; j < 2; ++j)                             \
      async_cp16(srcB[j] + (size_t)(T) * 128, BsB + (buf) * 16384 + dstB[j]); \
  } while (0)

  STAGE_G(0, 0);
  STAGE_G(1, 1);
  asm volatile("s_waitcnt vmcnt(6)" ::: "memory");
  __builtin_amdgcn_s_barrier();
  __builtin_amdgcn_sched_barrier(0);

#define GEMM_IT(T, BR, BS, DOSTAGE, DOBAR, CNT)                               \
  do {                                                                        \
    if (DOSTAGE) STAGE_G(BS, (T) + 2);                                        \
    half8 af[2][4], bf[2][4];                                                 \
    _Pragma("unroll") for (int kk = 0; kk < 2; ++kk)                          \
      _Pragma("unroll") for (int m = 0; m < 4; ++m)                           \
        af[kk][m] = *(const half8*)(AsB + (BR) * 32768 + abo[kk][m]);         \
    _Pragma("unroll") for (int kk = 0; kk < 2; ++kk)                          \
      _Pragma("unroll") for (int n = 0; n < 4; ++n)                           \
        bf[kk][n] = *(const half8*)(BsB + (BR) * 16384 + bbo[kk][n]);         \
    _Pragma("unroll") for (int kk = 0; kk < 2; ++kk)                          \
      _Pragma("unroll") for (int m = 0; m < 4; ++m)                           \
        _Pragma("unroll") for (int n = 0; n < 4; ++n)                         \
          acc[m][n] = __builtin_amdgcn_mfma_f32_16x16x32_f16(af[kk][m], bf[kk][n], acc[m][n], 0, 0, 0); \
    if (DOBAR) {                                                              \
      if (CNT) asm volatile("s_waitcnt vmcnt(6)" ::: "memory");               \
      else     asm volatile("s_waitcnt vmcnt(0)" ::: "memory");               \
      __builtin_amdgcn_s_barrier();                                           \
      __builtin_amdgcn_sched_barrier(0);                                      \
    }                                                                         \
  } while (0)

  for (int tb = 0; tb < 12; tb += 3) {
    GEMM_IT(tb,     0, 2, 1, 1, 1);
    GEMM_IT(tb + 1, 1, 0, 1, 1, 1);
    GEMM_IT(tb + 2, 2, 1, 1, 1, 1);
  }
  GEMM_IT(12, 0, 2, 1, 1, 1);
  GEMM_IT(13, 1, 0, 1, 1, 1);
  GEMM_IT(14, 2, 1, 0, 1, 0);
  GEMM_IT(15, 0, 1, 0, 0, 0);
#undef GEMM_IT
#undef STAGE_G

#pragma unroll
  for (int m = 0; m < 4; ++m) {
    const int Rb = m0 + wr * 64 + m * 16 + lg * 4;
#pragma unroll
    for (int n = 0; n < 4; ++n) {
      const int C = n0 + wc * 64 + n * 16 + l15;
      const float bv = bias[C];
#pragma unroll
      for (int i = 0; i < 4; ++i) {
        const int R = Rb + i;
        const float vv = acc[m][n][i] + bv;
        if (EPI == 3) {
          ((float*)out)[(size_t)R * 1024 + C] = vv;
        } else {
          const int b = R >> 11, t = R & 2047, hh = C >> 6, d = C & 63;
          if (EPI == 0)
            ((u16*)out)[((b * 16 + hh) * 2048 + t) * 64 + d] = f2h_bits(vv * 0.18033688f);
          else if (EPI == 1)
            ((u16*)out)[((b * 16 + hh) * 2048 + t) * 64 + d] = f2h_bits(vv);
          else
            ((u16*)out)[((b * 16 + hh) * 64 + d) * 2048 + t] = f2h_bits(vv);
        }
      }
    }
  }
}

template<int EPI>
__launch_bounds__(512)
__global__ void gemm_proj(const u16* __restrict__ A, const u16* __restrict__ Bt,
                          const float* __restrict__ bias, u16* __restrict__ out)
{
  __shared__ char AsB[3 * 32768];   // 96KB
  __shared__ char BsB[3 * 16384];   // 48KB
  gemm_body<EPI, u16>(A, Bt, bias, out, AsB, BsB);
}

__launch_bounds__(512)
__global__ void gemm_o(const u16* __restrict__ A, const u16* __restrict__ Bt,
                       const float* __restrict__ bias, float* __restrict__ out)
{
  __shared__ char AsB[3 * 32768];
  __shared__ char BsB[3 * 16384];
  gemm_body<3, float>(A, Bt, bias, out, AsB, BsB);
}

// ---------------- flash attention v4.1: precomputed fragment offsets ----------------
// K-frag and V-frag share the same offset table fo[4][2] (both use rows n*16+l15).
// Reads address SM_flat + compile-time buffer constant + fo -> folded ds immediates.
__launch_bounds__(512)
__global__ void attn_kernel(const u16* __restrict__ qh, const u16* __restrict__ kh,
                            const u16* __restrict__ vt, u16* __restrict__ O)
{
  __shared__ char SM[65536];   // K bufs [0,32KB), V bufs [32,64KB); Q prologue spans all
  const int tid = threadIdx.x, wave = tid >> 6, lane = tid & 63;
  const int l15 = lane & 15, lg = lane >> 4;
  const int swz = ((blockIdx.x & 7) << 5) | (blockIdx.x >> 3);   // XCD swizzle, [0,256)
  const int bh = swz >> 2;                 // b*16+h
  const int q0 = (swz & 3) << 9;           // 512 q-rows/block
  const int b = bh >> 4, h = bh & 15;

  const char* qbase = (const char*)(qh + (size_t)(bh * 2048 + q0) * 64);
  const char* kbase = (const char*)(kh + (size_t)bh * 2048 * 64);
  const char* vbase = (const char*)(vt + (size_t)bh * 64 * 2048);

  const bool isK = wave < 4;
  const char* ksrc[2]; int kdst[2];
  const char* vsrc[2]; int vdstA[2], vdstB[2];
#pragma unroll
  for (int j = 0; j < 2; ++j) {
    if (isK) {
      const int yb = wave * 2048 + j * 1024 + lane * 16;   // [0,8192)
      const int row = yb >> 7;
      ksrc[j] = kbase + (yb ^ ((row & 7) << 4));
      kdst[j] = yb;
      vsrc[j] = nullptr; vdstA[j] = vdstB[j] = 0;
    } else {
      const int u = (wave - 4) * 128 + j * 64 + lane;      // [0,512)
      const int d = u >> 3, a = u & 7;
      vsrc[j] = vbase + (size_t)d * 4096 + a * 16;
      const int n = a >> 1;
      const int s1 = 32 * (n >> 1) + 16 * (a & 1) + 4 * (n & 1);
      const int sw = (d & 7) << 4;
      vdstA[j] = (d * 128 + 2 * s1) ^ sw;
      vdstB[j] = (d * 128 + 2 * s1 + 16) ^ sw;
      ksrc[j] = nullptr; kdst[j] = 0;
    }
  }

  // fragment offset table (shared by K and V reads; loop-invariant)
  int fo[4][2];
#pragma unroll
  for (int n = 0; n < 4; ++n) {
    const int row = n * 16 + l15;
    const int a0 = (row * 128 + lg * 16) ^ ((row & 7) << 4);
    fo[n][0] = a0;
    fo[n][1] = a0 ^ 64;
  }

  // ---- prologue: Q (64KB = 512 rows x 128B) through SM; read 4 fragment groups ----
#pragma unroll
  for (int j = 0; j < 8; ++j) {
    const int x = j * 8192 + tid * 16;     // [0,65536)
    const int row = x >> 7;
    async_cp16(qbase + (x ^ ((row & 7) << 4)), SM + x);
  }
  __syncthreads();
  half8 aq[4][2];   // [G][k-half]
#pragma unroll
  for (int G = 0; G < 4; ++G) {
    const int qr = wave * 64 + G * 16 + l15;               // [0,512)
#pragma unroll
    for (int hh = 0; hh < 2; ++hh) {
      const int addr = (qr * 128 + hh * 64 + lg * 16) ^ ((qr & 7) << 4);
      aq[G][hh] = *(const half8*)(SM + addr);
    }
  }
  asm volatile("s_waitcnt lgkmcnt(0)" ::: "memory");
  __syncthreads();

  // ---- pipeline prologue: tiles 0,1 staged; va <- tiles 2,3 ----
  uint4 va[2][2];
  if (isK) {
    async_cp16(ksrc[0], SM + kdst[0]);
    async_cp16(ksrc[1], SM + kdst[1]);
    async_cp16(ksrc[0] + 8192, SM + 8192 + kdst[0]);
    async_cp16(ksrc[1] + 8192, SM + 8192 + kdst[1]);
    asm volatile("s_waitcnt vmcnt(0)" ::: "memory");
  } else {
#pragma unroll
    for (int tt = 0; tt < 2; ++tt)
#pragma unroll
      for (int j = 0; j < 2; ++j) {
        uint4 v = *(const uint4*)(vsrc[j] + (size_t)tt * 128);
        uint2 w0; w0.x = v.x; w0.y = v.y;
        uint2 w1; w1.x = v.z; w1.y = v.w;
        *(uint2*)(SM + 32768 + tt * 8192 + vdstA[j]) = w0;
        *(uint2*)(SM + 32768 + tt * 8192 + vdstB[j]) = w1;
      }
#pragma unroll
    for (int j = 0; j < 2; ++j) {
      va[0][j] = *(const uint4*)(vsrc[j] + 2 * 128);
      va[1][j] = *(const uint4*)(vsrc[j] + 3 * 128);
    }
    asm volatile("s_waitcnt lgkmcnt(0)" ::: "memory");
  }
  __builtin_amdgcn_s_barrier();
  __builtin_amdgcn_sched_barrier(0);

  half8 ones;
#pragma unroll
  for (int i = 0; i < 8; ++i) ones[i] = (_Float16)1.0f;

  const f32x4 fz = {0.f, 0.f, 0.f, 0.f};
  f32x4 o[4][4], osum[4];
#pragma unroll
  for (int i = 0; i < 4; ++i) {
#pragma unroll
    for (int G = 0; G < 4; ++G) o[i][G] = fz;
    osum[i] = fz;
  }

  // K reads: SM + BT*8192 + fo[n][h]; V reads: SM + 32768 + BT*8192 + fo[nd][h]
#define ATTN_TILE(BT)                                                           \
  do {                                                                          \
    half8 pa[4][2];                                                             \
    _Pragma("unroll") for (int hp = 0; hp < 2; ++hp) {                          \
      f32x4 s0[4], s1[4];                                                       \
      __builtin_amdgcn_s_setprio(1);                                            \
      {                                                                         \
        half8 bk0 = *(const half8*)(SM + (BT) * 8192 + fo[2*hp][0]);            \
        half8 bk1 = *(const half8*)(SM + (BT) * 8192 + fo[2*hp][1]);            \
        _Pragma("unroll") for (int G = 0; G < 4; ++G) {                         \
          s0[G] = __builtin_amdgcn_mfma_f32_16x16x32_f16(bk0, aq[G][0], fz, 0, 0, 0); \
          s0[G] = __builtin_amdgcn_mfma_f32_16x16x32_f16(bk1, aq[G][1], s0[G], 0, 0, 0); \
        }                                                                       \
      }                                                                         \
      {                                                                         \
        half8 bk0 = *(const half8*)(SM + (BT) * 8192 + fo[2*hp+1][0]);          \
        half8 bk1 = *(const half8*)(SM + (BT) * 8192 + fo[2*hp+1][1]);          \
        _Pragma("unroll") for (int G = 0; G < 4; ++G) {                         \
          s1[G] = __builtin_amdgcn_mfma_f32_16x16x32_f16(bk0, aq[G][0], fz, 0, 0, 0); \
          s1[G] = __builtin_amdgcn_mfma_f32_16x16x32_f16(bk1, aq[G][1], s1[G], 0, 0, 0); \
        }                                                                       \
      }                                                                         \
      __builtin_amdgcn_s_setprio(0);                                            \
      _Pragma("unroll") for (int G = 0; G < 4; ++G) {                           \
        union { u32 w[4]; half8 hv; } cv;                                       \
        cv.w[0] = pack2h(EXP2(s0[G][0]), EXP2(s0[G][1]));                       \
        cv.w[1] = pack2h(EXP2(s0[G][2]), EXP2(s0[G][3]));                       \
        cv.w[2] = pack2h(EXP2(s1[G][0]), EXP2(s1[G][1]));                       \
        cv.w[3] = pack2h(EXP2(s1[G][2]), EXP2(s1[G][3]));                       \
        pa[G][hp] = cv.hv;                                                      \
      }                                                                         \
    }                                                                           \
    __builtin_amdgcn_s_setprio(1);                                              \
    _Pragma("unroll") for (int G = 0; G < 4; ++G) {                             \
      osum[G] = __builtin_amdgcn_mfma_f32_16x16x32_f16(pa[G][0], ones, osum[G], 0, 0, 0); \
      osum[G] = __builtin_amdgcn_mfma_f32_16x16x32_f16(pa[G][1], ones, osum[G], 0, 0, 0); \
    }                                                                           \
    _Pragma("unroll") for (int nd = 0; nd < 4; ++nd) {                          \
      half8 bv0 = *(const half8*)(SM + 32768 + (BT) * 8192 + fo[nd][0]);        \
      half8 bv1 = *(const half8*)(SM + 32768 + (BT) * 8192 + fo[nd][1]);        \
      _Pragma("unroll") for (int G = 0; G < 4; ++G) {                           \
        o[nd][G] = __builtin_amdgcn_mfma_f32_16x16x32_f16(pa[G][0], bv0, o[nd][G], 0, 0, 0); \
        o[nd][G] = __builtin_amdgcn_mfma_f32_16x16x32_f16(pa[G][1], bv1, o[nd][G], 0, 0, 0); \
      }                                                                         \
    }                                                                           \
    __builtin_amdgcn_s_setprio(0);                                              \
  } while (0)

#define PERIOD(P, C0, C1, S0, S1, DOSTAGE, DOVA, DOBAR)                         \
  do {                                                                          \
    if (isK) {                                                                  \
      if (DOSTAGE) {                                                            \
        async_cp16(ksrc[0] + (size_t)(2*(P)+2) * 8192, SM + (S0) * 8192 + kdst[0]); \
        async_cp16(ksrc[1] + (size_t)(2*(P)+2) * 8192, SM + (S0) * 8192 + kdst[1]); \
        async_cp16(ksrc[0] + (size_t)(2*(P)+3) * 8192, SM + (S1) * 8192 + kdst[0]); \
        async_cp16(ksrc[1] + (size_t)(2*(P)+3) * 8192, SM + (S1) * 8192 + kdst[1]); \
      }                                                                         \
    } else {                                                                    \
      if (DOSTAGE) {                                                            \
        _Pragma("unroll") for (int j = 0; j < 2; ++j) {                         \
          uint2 w0, w1;                                                         \
          w0.x = va[0][j].x; w0.y = va[0][j].y;                                 \
          w1.x = va[0][j].z; w1.y = va[0][j].w;                                 \
          *(uint2*)(SM + 32768 + (S0) * 8192 + vdstA[j]) = w0;                  \
          *(uint2*)(SM + 32768 + (S0) * 8192 + vdstB[j]) = w1;                  \
          w0.x = va[1][j].x; w0.y = va[1][j].y;                                 \
          w1.x = va[1][j].z; w1.y = va[1][j].w;                                 \
          *(uint2*)(SM + 32768 + (S1) * 8192 + vdstA[j]) = w0;                  \
          *(uint2*)(SM + 32768 + (S1) * 8192 + vdstB[j]) = w1;                  \
        }                                                                       \
        if (DOVA) {                                                             \
          _Pragma("unroll") for (int j = 0; j < 2; ++j) {                       \
            va[0][j] = *(const uint4*)(vsrc[j] + (size_t)(2*(P)+4) * 128);      \
            va[1][j] = *(const uint4*)(vsrc[j] + (size_t)(2*(P)+5) * 128);      \
          }                                                                     \
        }                                                                       \
      }                                                                         \
    }                                                                           \
    ATTN_TILE(C0);                                                              \
    ATTN_TILE(C1);                                                              \
    if (DOBAR) {                                                                \
      if (isK) asm volatile("s_waitcnt vmcnt(0)" ::: "memory");                 \
      else     asm volatile("s_waitcnt lgkmcnt(0)" ::: "memory");               \
      __builtin_amdgcn_s_barrier();                                             \
      __builtin_amdgcn_sched_barrier(0);                                        \
    }                                                                           \
  } while (0)

  for (int pb = 0; pb < 14; pb += 2) {
    PERIOD(pb,     0, 1, 2, 3, 1, 1, 1);
    PERIOD(pb + 1, 2, 3, 0, 1, 1, 1, 1);
  }
  PERIOD(14, 0, 1, 2, 3, 1, 0, 1);
  PERIOD(15, 2, 3, 0, 1, 0, 0, 0);
#undef PERIOD
#undef ATTN_TILE

#pragma unroll
  for (int G = 0; G < 4; ++G)
#pragma unroll
    for (int i = 0; i < 4; ++i) {
      const float inv = 1.f / osum[G][i];
      const int t = q0 + wave * 64 + G * 16 + lg * 4 + i;
      u16* orow = O + ((size_t)(b * 2048 + t)) * 1024 + h * 64;
#pragma unroll
      for (int nd = 0; nd < 4; ++nd)
        orow[nd * 16 + l15] = f2h_bits(o[nd][G][i] * inv);
    }
}

extern "C" void kernel_launch(void* const* d_in, const int* in_sizes, int n_in,
                              void* d_out, int out_size, void* d_ws, size_t ws_size,
                              hipStream_t stream)
{
  const float* q  = (const float*)d_in[0];
  const float* k  = (const float*)d_in[1];
  const float* v  = (const float*)d_in[2];
  const float* Wq = (const float*)d_in[3];
  const float* bq = (const float*)d_in[4];
  const float* Wk = (const float*)d_in[5];
  const float* bk = (const float*)d_in[6];
  const float* Wv = (const float*)d_in[7];
  const float* bv = (const float*)d_in[8];
  const float* Wo = (const float*)d_in[9];
  const float* bo = (const float*)d_in[10];

  u16* W = (u16*)d_ws;
  const unsigned MB = 1u << 20;   // element (u16) units
  u16* wtq = W + 0 * MB;
  u16* wtk = W + 1 * MB;
  u16* wtv = W + 2 * MB;
  u16* wto = W + 3 * MB;
  u16* qhb = W + 4 * MB;
  u16* khb = W + 12 * MB;
  u16* vtb = W + 20 * MB;
  u16* Xb  = W + 28 * MB;   // xq (cvt) then attention output
  u16* xk  = W + 36 * MB;
  u16* xv  = W + 44 * MB;

  PParams pp;
  pp.W[0] = Wq; pp.W[1] = Wk; pp.W[2] = Wv; pp.W[3] = Wo;
  pp.Wt[0] = wtq; pp.Wt[1] = wtk; pp.Wt[2] = wtv; pp.Wt[3] = wto;
  pp.in[0] = (const float4*)q; pp.in[1] = (const float4*)k; pp.in[2] = (const float4*)v;
  pp.out[0] = Xb; pp.out[1] = xk; pp.out[2] = xv;
  prep<<<28672, 256, 0, stream>>>(pp);

  gemm_proj<0><<<256, 512, 0, stream>>>(Xb, wtq, bq, qhb);
  gemm_proj<1><<<256, 512, 0, stream>>>(xk, wtk, bk, khb);
  gemm_proj<2><<<256, 512, 0, stream>>>(xv, wtv, bv, vtb);

  attn_kernel<<<256, 512, 0, stream>>>(qhb, khb, vtb, Xb);

  gemm_o<<<256, 512, 0, stream>>>(Xb, wto, bo, (float*)d_out);
}